// Round 6
// baseline (154.199 us; speedup 1.0000x reference)
//
#include <hip/hip_runtime.h>
#include <hip/hip_bf16.h>

#define H_DIM 768
#define NHEAD 12
#define HDIM  64
#define S_LEN 2048
#define B_SZ  2
#define M_TOT (B_SZ * S_LEN)   // 4096
#define NQKV  (3 * H_DIM)      // 2304
#define LN_EPS 1e-5f
#define SM_C   0.1803368801f   // 0.125 * log2(e)

typedef __attribute__((ext_vector_type(8))) short bf16x8;
typedef __attribute__((ext_vector_type(4))) float f32x4;

static __device__ inline ushort f2bf(float x) {
    __hip_bfloat16 h = __float2bfloat16(x);
    ushort u;
    __builtin_memcpy(&u, &h, 2);
    return u;
}
static __device__ inline float bf2f(ushort u) {
    unsigned int v = ((unsigned int)u) << 16;
    float f;
    __builtin_memcpy(&f, &v, 4);
    return f;
}

#define GLDS16(g, l) __builtin_amdgcn_global_load_lds( \
    (const __attribute__((address_space(1))) void*)(g), \
    (__attribute__((address_space(3))) void*)(l), 16, 0, 0)

// ---------------- converters ----------------------------------------------
__global__ __launch_bounds__(256)
void convert_x(const float* __restrict__ src, ushort* __restrict__ dst)
{
    const int i = (blockIdx.x * 256 + threadIdx.x) * 4;
    f32x4 v = *(const f32x4*)(src + i);
    ushort4 o;
    o.x = f2bf(v[0]); o.y = f2bf(v[1]); o.z = f2bf(v[2]); o.w = f2bf(v[3]);
    *(ushort4*)(dst + i) = o;
}

__global__ __launch_bounds__(256)
void concat_bias(const float* __restrict__ bq, const float* __restrict__ bk,
                 const float* __restrict__ bv, float* __restrict__ dst)
{
    const int t = blockIdx.x * 256 + threadIdx.x;
    if (t < NQKV) {
        float v = (t < 768) ? bq[t] : (t < 1536) ? bk[t - 768] : bv[t - 1536];
        dst[t] = v;
    }
}

// W[k][n] f32 -> Wt[n][k] bf16 (z=0..2 into Wcat rows z*768.., z=3 into Wot)
__global__ __launch_bounds__(256)
void convert_w(const float* __restrict__ Wq, const float* __restrict__ Wk,
               const float* __restrict__ Wv, const float* __restrict__ Wo,
               ushort* __restrict__ Wcat, ushort* __restrict__ Wot)
{
    const int k0 = blockIdx.x * 64;
    const int n0 = blockIdx.y * 64;
    const int z  = blockIdx.z;
    const float* W = (z == 0) ? Wq : (z == 1) ? Wk : (z == 2) ? Wv : Wo;
    __shared__ ushort T[64][65];
    const int t = threadIdx.x;
    const int r = t >> 2, c0 = (t & 3) * 16;
    const float* src = W + (size_t)(k0 + r) * H_DIM + n0 + c0;
    #pragma unroll
    for (int j = 0; j < 16; j += 4) {
        f32x4 v = *(const f32x4*)(src + j);
        #pragma unroll
        for (int jj = 0; jj < 4; ++jj) T[r][c0 + j + jj] = f2bf(v[jj]);
    }
    __syncthreads();
    bf16x8 o0, o1;
    #pragma unroll
    for (int j = 0; j < 8; ++j) {
        o0[j] = (short)T[c0 + j][r];
        o1[j] = (short)T[c0 + 8 + j][r];
    }
    ushort* dst = (z < 3)
        ? Wcat + (size_t)(z * 768 + n0 + r) * H_DIM + k0 + c0
        : Wot  + (size_t)(n0 + r) * H_DIM + k0 + c0;
    *(bf16x8*)dst       = o0;
    *(bf16x8*)(dst + 8) = o1;
}

// ---------------- MFMA GEMM: out[m][n] = A[m][:]·Bt[n][:] + bias (+resid) --
template<int OUTMODE>   // 0: bf16 out, no resid; 1: f32 out + f32 resid
__global__ __launch_bounds__(256)
void gemm_mfma(const ushort* __restrict__ A, const ushort* __restrict__ Bt,
               const float* __restrict__ bias, const float* __restrict__ resid,
               void* __restrict__ outp, int M, int N, int K,
               int nscale, float sfac)
{
    __shared__ ushort As[128 * 32];
    __shared__ ushort Bs[128 * 32];
    const int bn = blockIdx.x * 128;
    const int bm = blockIdx.y * 128;
    const int t  = threadIdx.x;
    const int w  = t >> 6, l = t & 63;
    const int lg = l >> 4, lr = l & 15;
    const int wr = w >> 1, wc = w & 1;

    f32x4 acc[4][4];
    #pragma unroll
    for (int i = 0; i < 4; ++i)
        #pragma unroll
        for (int j = 0; j < 4; ++j) acc[i][j] = (f32x4){0.f, 0.f, 0.f, 0.f};

    for (int k0 = 0; k0 < K; k0 += 32) {
        #pragma unroll
        for (int it = 0; it < 2; ++it) {
            const int g = it * 256 + t;
            const int r = g >> 2, cb = (g & 3) * 8;
            GLDS16(A  + (size_t)(bm + r) * K + k0 + cb, (char*)As + g * 16);
            GLDS16(Bt + (size_t)(bn + r) * K + k0 + cb, (char*)Bs + g * 16);
        }
        __syncthreads();
        bf16x8 af[4], bfr[4];
        #pragma unroll
        for (int m16 = 0; m16 < 4; ++m16)
            af[m16] = *(const bf16x8*)&As[(wr * 64 + m16 * 16 + lr) * 32 + lg * 8];
        #pragma unroll
        for (int n16 = 0; n16 < 4; ++n16)
            bfr[n16] = *(const bf16x8*)&Bs[(wc * 64 + n16 * 16 + lr) * 32 + lg * 8];
        #pragma unroll
        for (int m16 = 0; m16 < 4; ++m16)
            #pragma unroll
            for (int n16 = 0; n16 < 4; ++n16)
                acc[m16][n16] = __builtin_amdgcn_mfma_f32_16x16x32_bf16(
                    af[m16], bfr[n16], acc[m16][n16], 0, 0, 0);
        __syncthreads();
    }

    #pragma unroll
    for (int m16 = 0; m16 < 4; ++m16) {
        #pragma unroll
        for (int n16 = 0; n16 < 4; ++n16) {
            const int col = bn + wc * 64 + n16 * 16 + lr;
            const float bcol = bias[col];
            #pragma unroll
            for (int r = 0; r < 4; ++r) {
                const int row = bm + wr * 64 + m16 * 16 + lg * 4 + r;
                float v = acc[m16][n16][r] + bcol;
                if (OUTMODE == 1) {
                    v += resid[(size_t)row * N + col];
                    ((float*)outp)[(size_t)row * N + col] = v;
                } else {
                    if (col < nscale) v *= sfac;
                    ((ushort*)outp)[(size_t)row * N + col] = f2bf(v);
                }
            }
        }
    }
}

// ---------------- V transpose: bf16 [b*S+s][2304] col h*64+d -> [b][h][d][s]
__global__ __launch_bounds__(256)
void transpose_v(const ushort* __restrict__ Vsrc, ushort* __restrict__ Vt)
{
    const int s0 = blockIdx.x * 64;
    const int bh = blockIdx.y;
    const int b  = bh / NHEAD, h = bh % NHEAD;
    const int t  = threadIdx.x;
    __shared__ ushort T[64][65];

    const int r  = t >> 2;
    const int c0 = (t & 3) * 16;
    const ushort* src = Vsrc + (size_t)(b * S_LEN + s0 + r) * NQKV + h * HDIM + c0;
    bf16x8 a0 = *(const bf16x8*)src;
    bf16x8 a1 = *(const bf16x8*)(src + 8);
    #pragma unroll
    for (int j = 0; j < 8; ++j) { T[r][c0 + j] = a0[j]; T[r][c0 + 8 + j] = a1[j]; }
    __syncthreads();

    const int d = t >> 2, sc0 = (t & 3) * 16;
    bf16x8 o0, o1;
    #pragma unroll
    for (int j = 0; j < 8; ++j) {
        o0[j] = (short)T[sc0 + j][d];
        o1[j] = (short)T[sc0 + 8 + j][d];
    }
    ushort* dst = Vt + ((size_t)(b * NHEAD + h) * HDIM + d) * S_LEN + s0 + sc0;
    *(bf16x8*)dst       = o0;
    *(bf16x8*)(dst + 8) = o1;
}

// ---------------- MFMA flash attention, split-KV ---------------------------
// blockIdx.z = (b<<1)|half; each block covers kv in [half*1024, half*1024+1024).
// Writes UNNORMALIZED partial O (bf16) + partial denominator l (f32);
// combine_kernel sums the two halves and normalizes (no-max softmax => sums add).
#define KT     64
#define ATT_QT 64
#define KVHALF (S_LEN / 2)

__global__ __launch_bounds__(256)
void attn_mfma(const ushort* __restrict__ Qbf, const ushort* __restrict__ Kbf,
               const ushort* __restrict__ Vt, const float* __restrict__ mask,
               ushort* __restrict__ Pp, float* __restrict__ lp)
{
    const int qt = blockIdx.x, h = blockIdx.y;
    const int b  = blockIdx.z >> 1, half = blockIdx.z & 1;
    const int t  = threadIdx.x;
    const int w  = t >> 6, l = t & 63;
    const int lg = l >> 4, lr = l & 15;
    const int q0 = qt * ATT_QT;
    const int kb0 = half * KVHALF;

    __shared__ ushort Ks[2][KT][64];     // [kv][d]   8 KB per buf, swizzled
    __shared__ ushort Vs[2][HDIM][64];   // [d][kv]   8 KB per buf, swizzled
    __shared__ ushort Ps[4][16][64];     // per-wave P [q][kv], swizzled

    bool qn[4];
    #pragma unroll
    for (int r = 0; r < 4; ++r)
        qn[r] = (mask[b * S_LEN + q0 + w * 16 + lg * 4 + r] < 0.f);

    // Q A-fragments (pre-scaled by SM_C in the QKV GEMM epilogue)
    bf16x8 qa[2];
    {
        const ushort* qsrc = Qbf + (size_t)(b * S_LEN + q0 + w * 16 + lr) * NQKV
                           + h * HDIM + lg * 8;
        qa[0] = *(const bf16x8*)qsrc;
        qa[1] = *(const bf16x8*)(qsrc + 32);
    }

    // staging geometry (T2 swizzle: source column pre-swizzled, LDS linear)
    const int srow = w * 16 + (l >> 3);
    const int scol = ((l & 7) ^ (l >> 3)) * 8;
    const ushort* kp0 = Kbf + (size_t)(b * S_LEN + kb0 + srow) * NQKV + h * HDIM + scol;
    const ushort* kp1 = kp0 + (size_t)8 * NQKV;
    const ushort* vp0 = Vt + ((size_t)(b * NHEAD + h) * HDIM + srow) * S_LEN + kb0 + scol;
    const ushort* vp1 = vp0 + (size_t)8 * S_LEN;
    char* ldsK = (char*)Ks + w * 2048 + l * 16;
    char* ldsV = (char*)Vs + w * 2048 + l * 16;

    // prologue: stage tile 0 into buffer 0
    GLDS16(kp0, ldsK);        GLDS16(kp1, ldsK + 1024);
    GLDS16(vp0, ldsV);        GLDS16(vp1, ldsV + 1024);
    kp0 += (size_t)KT * NQKV; kp1 += (size_t)KT * NQKV;
    vp0 += KT;                vp1 += KT;
    __syncthreads();

    float l_r[4] = {0.f, 0.f, 0.f, 0.f};
    f32x4 accO[4];
    #pragma unroll
    for (int ct = 0; ct < 4; ++ct) accO[ct] = (f32x4){0.f, 0.f, 0.f, 0.f};

    const int  swz = (lr & 7) << 4;
    char* PsW = (char*)Ps + w * 2048;

    int cur = 0;
    for (int k0 = kb0; k0 < kb0 + KVHALF; k0 += KT) {
        // kv-mask -> additive arg {0, -1e30} (4 cndmask per tile)
        float karr[4];
        #pragma unroll
        for (int ct = 0; ct < 4; ++ct) {
            const float km = mask[b * S_LEN + k0 + 16 * ct + lr];
            karr[ct] = (km >= 0.f) ? 0.f : -1e30f;
        }

        // async prefetch of next tile into the other buffer
        if (k0 + KT < kb0 + KVHALF) {
            char* lk = ldsK + (cur ^ 1) * 8192;
            char* lv = ldsV + (cur ^ 1) * 8192;
            GLDS16(kp0, lk);  GLDS16(kp1, lk + 1024);
            GLDS16(vp0, lv);  GLDS16(vp1, lv + 1024);
            kp0 += (size_t)KT * NQKV; kp1 += (size_t)KT * NQKV;
            vp0 += KT;                vp1 += KT;
        }

        // ---- S = Q·K^T (softmax scale already folded into Q) ----
        const char* KsB = (const char*)Ks + cur * 8192;
        f32x4 sc[4];
        __builtin_amdgcn_s_setprio(1);
        #pragma unroll
        for (int ct = 0; ct < 4; ++ct) {
            f32x4 acc = (f32x4){0.f, 0.f, 0.f, 0.f};
            #pragma unroll
            for (int kb = 0; kb < 2; ++kb) {
                bf16x8 bk = *(const bf16x8*)(KsB + (16 * ct + lr) * 128
                                             + ((lg * 16 + kb * 64) ^ swz));
                acc = __builtin_amdgcn_mfma_f32_16x16x32_bf16(qa[kb], bk, acc, 0, 0, 0);
            }
            sc[ct] = acc;
        }
        __builtin_amdgcn_s_setprio(0);

        // ---- p = exp2(arg), masked; accumulate denominator per-lane ----
        #pragma unroll
        for (int r = 0; r < 4; ++r) {
            const int qrow = lg * 4 + r;
            const int qsw  = (qrow & 7) << 4;
            #pragma unroll
            for (int ct = 0; ct < 4; ++ct) {
                float arg = sc[ct][r] + karr[ct];
                arg = qn[r] ? 0.f : arg;
                const float p = exp2f(arg);
                l_r[r] += p;
                *(ushort*)(PsW + qrow * 128 + ((32 * ct + 2 * lr) ^ qsw)) = f2bf(p);
            }
        }

        // ---- O += P·V ----
        const char* VsB = (const char*)Vs + cur * 8192;
        __builtin_amdgcn_s_setprio(1);
        #pragma unroll
        for (int kvb = 0; kvb < 2; ++kvb) {
            bf16x8 pa = *(const bf16x8*)(PsW + lr * 128
                                         + ((lg * 16 + kvb * 64) ^ swz));
            #pragma unroll
            for (int ct = 0; ct < 4; ++ct) {
                bf16x8 bv = *(const bf16x8*)(VsB + (16 * ct + lr) * 128
                                             + ((lg * 16 + kvb * 64) ^ swz));
                accO[ct] = __builtin_amdgcn_mfma_f32_16x16x32_bf16(pa, bv, accO[ct], 0, 0, 0);
            }
        }
        __builtin_amdgcn_s_setprio(0);

        __syncthreads();
        cur ^= 1;
    }

    // denominator reduce across the 16 lanes of each row group
    #pragma unroll
    for (int r = 0; r < 4; ++r) {
        float s = l_r[r];
        #pragma unroll
        for (int off = 1; off < 16; off <<= 1)
            s += __shfl_xor(s, off, 64);
        l_r[r] = s;
    }

    // write unnormalized partial O (bf16) + l (f32)
    const size_t MN = (size_t)M_TOT * H_DIM;
    #pragma unroll
    for (int r = 0; r < 4; ++r) {
        const int m = b * S_LEN + q0 + w * 16 + lg * 4 + r;
        const size_t base = (size_t)half * MN + (size_t)m * H_DIM + h * HDIM;
        #pragma unroll
        for (int ct = 0; ct < 4; ++ct)
            Pp[base + 16 * ct + lr] = f2bf(accO[ct][r]);
        if (lr == 0)
            lp[half * (M_TOT * NHEAD) + m * NHEAD + h] = l_r[r];
    }
}

// ---------------- combine: ctx = (P0+P1)/(l0+l1) ---------------------------
__global__ __launch_bounds__(256)
void combine_kernel(const ushort* __restrict__ Pp, const float* __restrict__ lp,
                    ushort* __restrict__ ctx)
{
    const int idx = blockIdx.x * 256 + threadIdx.x;   // over M_TOT*96
    const int m  = idx / 96;
    const int c8 = idx % 96;
    const int c  = c8 * 8;
    const int h  = c8 >> 3;
    const size_t MN = (size_t)M_TOT * H_DIM;

    const float lsum = lp[m * NHEAD + h] + lp[M_TOT * NHEAD + m * NHEAD + h];
    const float inv  = 1.0f / lsum;

    bf16x8 a = *(const bf16x8*)(Pp + (size_t)m * H_DIM + c);
    bf16x8 b = *(const bf16x8*)(Pp + MN + (size_t)m * H_DIM + c);
    bf16x8 o;
    #pragma unroll
    for (int j = 0; j < 8; ++j)
        o[j] = (short)f2bf((bf2f((ushort)a[j]) + bf2f((ushort)b[j])) * inv);
    *(bf16x8*)(ctx + (size_t)m * H_DIM + c) = o;
}

// ---------------- LayerNorm ------------------------------------------------
__global__ __launch_bounds__(256)
void ln_kernel(const float* __restrict__ Hbuf, const float* __restrict__ gamma,
               const float* __restrict__ beta, float* __restrict__ out)
{
    const int m = blockIdx.x;
    const int t = threadIdx.x;
    const float* row = Hbuf + (size_t)m * H_DIM;
    __shared__ float red[256];
    float x[3];
    #pragma unroll
    for (int i = 0; i < 3; ++i) x[i] = row[t + i * 256];

    red[t] = x[0] + x[1] + x[2];
    __syncthreads();
    for (int off = 128; off > 0; off >>= 1) {
        if (t < off) red[t] += red[t + off];
        __syncthreads();
    }
    const float mu = red[0] * (1.0f / H_DIM);
    __syncthreads();

    float d0 = x[0] - mu, d1 = x[1] - mu, d2 = x[2] - mu;
    red[t] = d0 * d0 + d1 * d1 + d2 * d2;
    __syncthreads();
    for (int off = 128; off > 0; off >>= 1) {
        if (t < off) red[t] += red[t + off];
        __syncthreads();
    }
    const float var  = red[0] * (1.0f / H_DIM);
    const float rstd = rsqrtf(var + LN_EPS);
    #pragma unroll
    for (int i = 0; i < 3; ++i) {
        int c = t + i * 256;
        out[(size_t)m * H_DIM + c] = (x[i] - mu) * rstd * gamma[c] + beta[c];
    }
}

// ---------------------------------------------------------------------------
extern "C" void kernel_launch(void* const* d_in, const int* in_sizes, int n_in,
                              void* d_out, int out_size, void* d_ws, size_t ws_size,
                              hipStream_t stream)
{
    const float* hs   = (const float*)d_in[0];
    const float* mask = (const float*)d_in[1];
    const float* Wq   = (const float*)d_in[2];
    const float* bq   = (const float*)d_in[3];
    const float* Wk   = (const float*)d_in[4];
    const float* bk   = (const float*)d_in[5];
    const float* Wv   = (const float*)d_in[6];
    const float* bv   = (const float*)d_in[7];
    const float* Wo   = (const float*)d_in[8];
    const float* bo   = (const float*)d_in[9];
    const float* g    = (const float*)d_in[10];
    const float* be   = (const float*)d_in[11];
    float* out = (float*)d_out;

    char* base = (char*)d_ws;
    ushort* Xbf    = (ushort*)(base);                    //  6,291,456 B
    ushort* QKVbf  = (ushort*)(base + 6291456);          // 18,874,368 B
    ushort* Wcat   = (ushort*)(base + 25165824);         //  3,538,944 B (lp after QKV gemm)
    ushort* Wot    = (ushort*)(base + 28704768);         //  1,179,648 B
    float*  bcat   = (float*) (base + 29884416);         //      9,216 B
    ushort* Vt     = (ushort*)(base + 29893632);         //  6,291,456 B
    ushort* Cbf    = (ushort*)(base + 36185088);         //  6,291,456 B
    float*  Hb     = (float*) (base + 42476544);         // 12,582,912 B (Pp before out-GEMM)
    float*  lp     = (float*) (base + 25165824);         // reuse Wcat region (393,216 B)
    ushort* Pp     = (ushort*)(base + 42476544);         // reuse Hb region (12,582,912 B)

    convert_x<<<M_TOT * H_DIM / 1024, 256, 0, stream>>>(hs, Xbf);
    concat_bias<<<9, 256, 0, stream>>>(bq, bk, bv, bcat);
    convert_w<<<dim3(12, 12, 4), 256, 0, stream>>>(Wq, Wk, Wv, Wo, Wcat, Wot);

    // Q columns (< 768) pre-scaled by 0.125*log2(e) so attention can exp2 directly
    gemm_mfma<0><<<dim3(NQKV / 128, M_TOT / 128), 256, 0, stream>>>(
        Xbf, Wcat, bcat, nullptr, QKVbf, M_TOT, NQKV, H_DIM, 768, SM_C);

    transpose_v<<<dim3(S_LEN / 64, B_SZ * NHEAD), 256, 0, stream>>>(QKVbf + 1536, Vt);

    attn_mfma<<<dim3(S_LEN / ATT_QT, NHEAD, B_SZ * 2), 256, 0, stream>>>(
        QKVbf, QKVbf + 768, Vt, mask, Pp, lp);

    combine_kernel<<<M_TOT * 96 / 256, 256, 0, stream>>>(Pp, lp, Cbf);

    gemm_mfma<1><<<dim3(H_DIM / 128, M_TOT / 128), 256, 0, stream>>>(
        Cbf, Wot, bo, hs, Hb, M_TOT, H_DIM, H_DIM, 0, 1.0f);

    ln_kernel<<<M_TOT, 256, 0, stream>>>(Hb, g, be, out);
}

// Round 7
// 146.265 us; speedup vs baseline: 1.0542x; 1.0542x over previous
//
#include <hip/hip_runtime.h>
#include <hip/hip_bf16.h>

#define H_DIM 768
#define NHEAD 12
#define HDIM  64
#define S_LEN 2048
#define B_SZ  2
#define M_TOT (B_SZ * S_LEN)   // 4096
#define NQKV  (3 * H_DIM)      // 2304
#define LN_EPS 1e-5f
#define SM_C   0.1803368801f   // 0.125 * log2(e)

typedef __attribute__((ext_vector_type(8))) short bf16x8;
typedef __attribute__((ext_vector_type(4))) float f32x4;

static __device__ inline ushort f2bf(float x) {
    __hip_bfloat16 h = __float2bfloat16(x);
    ushort u;
    __builtin_memcpy(&u, &h, 2);
    return u;
}
static __device__ inline float bf2f(ushort u) {
    unsigned int v = ((unsigned int)u) << 16;
    float f;
    __builtin_memcpy(&f, &v, 4);
    return f;
}

#define GLDS16(g, l) __builtin_amdgcn_global_load_lds( \
    (const __attribute__((address_space(1))) void*)(g), \
    (__attribute__((address_space(3))) void*)(l), 16, 0, 0)

// ---------------- converters ----------------------------------------------
__global__ __launch_bounds__(256)
void convert_x(const float* __restrict__ src, ushort* __restrict__ dst)
{
    const int i = (blockIdx.x * 256 + threadIdx.x) * 4;
    f32x4 v = *(const f32x4*)(src + i);
    ushort4 o;
    o.x = f2bf(v[0]); o.y = f2bf(v[1]); o.z = f2bf(v[2]); o.w = f2bf(v[3]);
    *(ushort4*)(dst + i) = o;
}

__global__ __launch_bounds__(256)
void concat_bias(const float* __restrict__ bq, const float* __restrict__ bk,
                 const float* __restrict__ bv, float* __restrict__ dst)
{
    const int t = blockIdx.x * 256 + threadIdx.x;
    if (t < NQKV) {
        float v = (t < 768) ? bq[t] : (t < 1536) ? bk[t - 768] : bv[t - 1536];
        dst[t] = v;
    }
}

// W[k][n] f32 -> Wt[n][k] bf16 (z=0..2 into Wcat rows z*768.., z=3 into Wot)
__global__ __launch_bounds__(256)
void convert_w(const float* __restrict__ Wq, const float* __restrict__ Wk,
               const float* __restrict__ Wv, const float* __restrict__ Wo,
               ushort* __restrict__ Wcat, ushort* __restrict__ Wot)
{
    const int k0 = blockIdx.x * 64;
    const int n0 = blockIdx.y * 64;
    const int z  = blockIdx.z;
    const float* W = (z == 0) ? Wq : (z == 1) ? Wk : (z == 2) ? Wv : Wo;
    __shared__ ushort T[64][65];
    const int t = threadIdx.x;
    const int r = t >> 2, c0 = (t & 3) * 16;
    const float* src = W + (size_t)(k0 + r) * H_DIM + n0 + c0;
    #pragma unroll
    for (int j = 0; j < 16; j += 4) {
        f32x4 v = *(const f32x4*)(src + j);
        #pragma unroll
        for (int jj = 0; jj < 4; ++jj) T[r][c0 + j + jj] = f2bf(v[jj]);
    }
    __syncthreads();
    bf16x8 o0, o1;
    #pragma unroll
    for (int j = 0; j < 8; ++j) {
        o0[j] = (short)T[c0 + j][r];
        o1[j] = (short)T[c0 + 8 + j][r];
    }
    ushort* dst = (z < 3)
        ? Wcat + (size_t)(z * 768 + n0 + r) * H_DIM + k0 + c0
        : Wot  + (size_t)(n0 + r) * H_DIM + k0 + c0;
    *(bf16x8*)dst       = o0;
    *(bf16x8*)(dst + 8) = o1;
}

// ---------------- MFMA GEMM: out[m][n] = A[m][:]·Bt[n][:] + bias (+resid) --
template<int OUTMODE>   // 0: bf16 out, no resid; 1: f32 out + f32 resid
__global__ __launch_bounds__(256)
void gemm_mfma(const ushort* __restrict__ A, const ushort* __restrict__ Bt,
               const float* __restrict__ bias, const float* __restrict__ resid,
               void* __restrict__ outp, int M, int N, int K,
               int nscale, float sfac)
{
    __shared__ ushort As[128 * 32];
    __shared__ ushort Bs[128 * 32];
    const int bn = blockIdx.x * 128;
    const int bm = blockIdx.y * 128;
    const int t  = threadIdx.x;
    const int w  = t >> 6, l = t & 63;
    const int lg = l >> 4, lr = l & 15;
    const int wr = w >> 1, wc = w & 1;

    f32x4 acc[4][4];
    #pragma unroll
    for (int i = 0; i < 4; ++i)
        #pragma unroll
        for (int j = 0; j < 4; ++j) acc[i][j] = (f32x4){0.f, 0.f, 0.f, 0.f};

    for (int k0 = 0; k0 < K; k0 += 32) {
        #pragma unroll
        for (int it = 0; it < 2; ++it) {
            const int g = it * 256 + t;
            const int r = g >> 2, cb = (g & 3) * 8;
            GLDS16(A  + (size_t)(bm + r) * K + k0 + cb, (char*)As + g * 16);
            GLDS16(Bt + (size_t)(bn + r) * K + k0 + cb, (char*)Bs + g * 16);
        }
        __syncthreads();
        bf16x8 af[4], bfr[4];
        #pragma unroll
        for (int m16 = 0; m16 < 4; ++m16)
            af[m16] = *(const bf16x8*)&As[(wr * 64 + m16 * 16 + lr) * 32 + lg * 8];
        #pragma unroll
        for (int n16 = 0; n16 < 4; ++n16)
            bfr[n16] = *(const bf16x8*)&Bs[(wc * 64 + n16 * 16 + lr) * 32 + lg * 8];
        #pragma unroll
        for (int m16 = 0; m16 < 4; ++m16)
            #pragma unroll
            for (int n16 = 0; n16 < 4; ++n16)
                acc[m16][n16] = __builtin_amdgcn_mfma_f32_16x16x32_bf16(
                    af[m16], bfr[n16], acc[m16][n16], 0, 0, 0);
        __syncthreads();
    }

    #pragma unroll
    for (int m16 = 0; m16 < 4; ++m16) {
        #pragma unroll
        for (int n16 = 0; n16 < 4; ++n16) {
            const int col = bn + wc * 64 + n16 * 16 + lr;
            const float bcol = bias[col];
            #pragma unroll
            for (int r = 0; r < 4; ++r) {
                const int row = bm + wr * 64 + m16 * 16 + lg * 4 + r;
                float v = acc[m16][n16][r] + bcol;
                if (OUTMODE == 1) {
                    v += resid[(size_t)row * N + col];
                    ((float*)outp)[(size_t)row * N + col] = v;
                } else {
                    if (col < nscale) v *= sfac;
                    ((ushort*)outp)[(size_t)row * N + col] = f2bf(v);
                }
            }
        }
    }
}

// ---------------- V transpose: bf16 [b*S+s][2304] col h*64+d -> [b][h][d][s]
__global__ __launch_bounds__(256)
void transpose_v(const ushort* __restrict__ Vsrc, ushort* __restrict__ Vt)
{
    const int s0 = blockIdx.x * 64;
    const int bh = blockIdx.y;
    const int b  = bh / NHEAD, h = bh % NHEAD;
    const int t  = threadIdx.x;
    __shared__ ushort T[64][65];

    const int r  = t >> 2;
    const int c0 = (t & 3) * 16;
    const ushort* src = Vsrc + (size_t)(b * S_LEN + s0 + r) * NQKV + h * HDIM + c0;
    bf16x8 a0 = *(const bf16x8*)src;
    bf16x8 a1 = *(const bf16x8*)(src + 8);
    #pragma unroll
    for (int j = 0; j < 8; ++j) { T[r][c0 + j] = a0[j]; T[r][c0 + 8 + j] = a1[j]; }
    __syncthreads();

    const int d = t >> 2, sc0 = (t & 3) * 16;
    bf16x8 o0, o1;
    #pragma unroll
    for (int j = 0; j < 8; ++j) {
        o0[j] = (short)T[sc0 + j][d];
        o1[j] = (short)T[sc0 + 8 + j][d];
    }
    ushort* dst = Vt + ((size_t)(b * NHEAD + h) * HDIM + d) * S_LEN + s0 + sc0;
    *(bf16x8*)dst       = o0;
    *(bf16x8*)(dst + 8) = o1;
}

// ---------------- MFMA flash attention, split-KV, 32q/wave -----------------
// blockIdx.z = (b<<1)|half; kv range [half*1024, half*1024+1024).
// Each wave owns 32 q rows (2 groups of 16). Unnormalized partial O (bf16)
// + partial denominator l (f32); combine_kernel sums halves and normalizes.
#define KT     64
#define ATT_QT 128
#define KVHALF (S_LEN / 2)

__global__ __launch_bounds__(256, 3)
void attn_mfma(const ushort* __restrict__ Qbf, const ushort* __restrict__ Kbf,
               const ushort* __restrict__ Vt, const float* __restrict__ mask,
               ushort* __restrict__ Pp, float* __restrict__ lp)
{
    const int qt = blockIdx.x, h = blockIdx.y;
    const int b  = blockIdx.z >> 1, half = blockIdx.z & 1;
    const int t  = threadIdx.x;
    const int w  = t >> 6, l = t & 63;
    const int lg = l >> 4, lr = l & 15;
    const int q0 = qt * ATT_QT;
    const int kb0 = half * KVHALF;

    __shared__ ushort Ks[2][KT][64];     // [kv][d]  8 KB/buf, swizzled
    __shared__ ushort Vs[2][HDIM][64];   // [d][kv]  8 KB/buf, swizzled
    __shared__ ushort Ps[4][32][64];     // per-wave P [q][kv] 16 KB, swizzled
    __shared__ float  kmarg[KVHALF];     // 4 KB: 0 valid / -1e30 masked

    // stage kv-mask args once (coalesced f32x4)
    {
        const int i = t * 4;
        f32x4 v = *(const f32x4*)(mask + b * S_LEN + kb0 + i);
        #pragma unroll
        for (int j = 0; j < 4; ++j)
            kmarg[i + j] = (v[j] >= 0.f) ? 0.f : -1e30f;
    }

    // q-row validity, 2 groups x 4 rows
    bool qn[2][4];
    #pragma unroll
    for (int qg = 0; qg < 2; ++qg)
        #pragma unroll
        for (int r = 0; r < 4; ++r)
            qn[qg][r] = (mask[b * S_LEN + q0 + w * 32 + qg * 16 + lg * 4 + r] < 0.f);

    // Q A-fragments (pre-scaled by SM_C in QKV GEMM epilogue)
    bf16x8 qa[2][2];
    #pragma unroll
    for (int qg = 0; qg < 2; ++qg) {
        const ushort* qsrc = Qbf
            + (size_t)(b * S_LEN + q0 + w * 32 + qg * 16 + lr) * NQKV
            + h * HDIM + lg * 8;
        qa[qg][0] = *(const bf16x8*)qsrc;
        qa[qg][1] = *(const bf16x8*)(qsrc + 32);
    }

    // staging geometry (T2 swizzle: source column pre-swizzled, LDS linear)
    const int srow = w * 16 + (l >> 3);
    const int scol = ((l & 7) ^ (l >> 3)) * 8;
    const ushort* kp0 = Kbf + (size_t)(b * S_LEN + kb0 + srow) * NQKV + h * HDIM + scol;
    const ushort* kp1 = kp0 + (size_t)8 * NQKV;
    const ushort* vp0 = Vt + ((size_t)(b * NHEAD + h) * HDIM + srow) * S_LEN + kb0 + scol;
    const ushort* vp1 = vp0 + (size_t)8 * S_LEN;
    char* ldsK = (char*)Ks + w * 2048 + l * 16;
    char* ldsV = (char*)Vs + w * 2048 + l * 16;

    // prologue: stage tile 0 into buffer 0
    GLDS16(kp0, ldsK);        GLDS16(kp1, ldsK + 1024);
    GLDS16(vp0, ldsV);        GLDS16(vp1, ldsV + 1024);
    kp0 += (size_t)KT * NQKV; kp1 += (size_t)KT * NQKV;
    vp0 += KT;                vp1 += KT;
    __syncthreads();

    float l_r[2][4] = {{0.f,0.f,0.f,0.f},{0.f,0.f,0.f,0.f}};
    f32x4 accO[2][4];
    #pragma unroll
    for (int qg = 0; qg < 2; ++qg)
        #pragma unroll
        for (int ct = 0; ct < 4; ++ct) accO[qg][ct] = (f32x4){0.f,0.f,0.f,0.f};

    const int  swz = (lr & 7) << 4;
    char* PsW = (char*)Ps + w * 4096;

    int cur = 0;
    for (int k0 = kb0; k0 < kb0 + KVHALF; k0 += KT) {
        // kv-mask additive args from LDS (broadcast across lg groups)
        float karr[4];
        #pragma unroll
        for (int ct = 0; ct < 4; ++ct)
            karr[ct] = kmarg[(k0 - kb0) + 16 * ct + lr];

        // async prefetch of next tile into the other buffer
        if (k0 + KT < kb0 + KVHALF) {
            char* lk = ldsK + (cur ^ 1) * 8192;
            char* lv = ldsV + (cur ^ 1) * 8192;
            GLDS16(kp0, lk);  GLDS16(kp1, lk + 1024);
            GLDS16(vp0, lv);  GLDS16(vp1, lv + 1024);
            kp0 += (size_t)KT * NQKV; kp1 += (size_t)KT * NQKV;
            vp0 += KT;                vp1 += KT;
        }

        // ---- S = Q·K^T (scale folded into Q); K-frags shared across 2 qg ----
        const char* KsB = (const char*)Ks + cur * 8192;
        f32x4 sc[2][4];
        __builtin_amdgcn_s_setprio(1);
        #pragma unroll
        for (int ct = 0; ct < 4; ++ct) {
            bf16x8 bk0 = *(const bf16x8*)(KsB + (16 * ct + lr) * 128 + ((lg * 16) ^ swz));
            bf16x8 bk1 = *(const bf16x8*)(KsB + (16 * ct + lr) * 128 + ((lg * 16 + 64) ^ swz));
            #pragma unroll
            for (int qg = 0; qg < 2; ++qg) {
                f32x4 a = __builtin_amdgcn_mfma_f32_16x16x32_bf16(
                    qa[qg][0], bk0, (f32x4){0.f,0.f,0.f,0.f}, 0, 0, 0);
                sc[qg][ct] = __builtin_amdgcn_mfma_f32_16x16x32_bf16(
                    qa[qg][1], bk1, a, 0, 0, 0);
            }
        }
        __builtin_amdgcn_s_setprio(0);

        // ---- p = exp2(arg); per-lane denominator accumulate ----
        #pragma unroll
        for (int qg = 0; qg < 2; ++qg) {
            #pragma unroll
            for (int r = 0; r < 4; ++r) {
                const int qrow = qg * 16 + lg * 4 + r;
                const int qsw  = (qrow & 7) << 4;
                #pragma unroll
                for (int ct = 0; ct < 4; ++ct) {
                    float arg = sc[qg][ct][r] + karr[ct];
                    arg = qn[qg][r] ? 0.f : arg;
                    const float p = exp2f(arg);
                    l_r[qg][r] += p;
                    *(ushort*)(PsW + qrow * 128 + ((32 * ct + 2 * lr) ^ qsw)) = f2bf(p);
                }
            }
        }

        // ---- O += P·V ; V-frags shared across 2 qg ----
        const char* VsB = (const char*)Vs + cur * 8192;
        __builtin_amdgcn_s_setprio(1);
        #pragma unroll
        for (int kvb = 0; kvb < 2; ++kvb) {
            bf16x8 pa0 = *(const bf16x8*)(PsW + lr * 128
                                          + ((lg * 16 + kvb * 64) ^ swz));
            bf16x8 pa1 = *(const bf16x8*)(PsW + (16 + lr) * 128
                                          + ((lg * 16 + kvb * 64) ^ swz));
            #pragma unroll
            for (int ct = 0; ct < 4; ++ct) {
                bf16x8 bv = *(const bf16x8*)(VsB + (16 * ct + lr) * 128
                                             + ((lg * 16 + kvb * 64) ^ swz));
                accO[0][ct] = __builtin_amdgcn_mfma_f32_16x16x32_bf16(pa0, bv, accO[0][ct], 0, 0, 0);
                accO[1][ct] = __builtin_amdgcn_mfma_f32_16x16x32_bf16(pa1, bv, accO[1][ct], 0, 0, 0);
            }
        }
        __builtin_amdgcn_s_setprio(0);

        __syncthreads();
        cur ^= 1;
    }

    // denominator reduce across the 16 lanes of each row group
    #pragma unroll
    for (int qg = 0; qg < 2; ++qg)
        #pragma unroll
        for (int r = 0; r < 4; ++r) {
            float s = l_r[qg][r];
            #pragma unroll
            for (int off = 1; off < 16; off <<= 1)
                s += __shfl_xor(s, off, 64);
            l_r[qg][r] = s;
        }

    // write unnormalized partial O (bf16) + l (f32)
    const size_t MN = (size_t)M_TOT * H_DIM;
    #pragma unroll
    for (int qg = 0; qg < 2; ++qg) {
        #pragma unroll
        for (int r = 0; r < 4; ++r) {
            const int m = b * S_LEN + q0 + w * 32 + qg * 16 + lg * 4 + r;
            const size_t base = (size_t)half * MN + (size_t)m * H_DIM + h * HDIM;
            #pragma unroll
            for (int ct = 0; ct < 4; ++ct)
                Pp[base + 16 * ct + lr] = f2bf(accO[qg][ct][r]);
            if (lr == 0)
                lp[half * (M_TOT * NHEAD) + m * NHEAD + h] = l_r[qg][r];
        }
    }
}

// ---------------- combine: ctx = (P0+P1)/(l0+l1) ---------------------------
__global__ __launch_bounds__(256)
void combine_kernel(const ushort* __restrict__ Pp, const float* __restrict__ lp,
                    ushort* __restrict__ ctx)
{
    const int idx = blockIdx.x * 256 + threadIdx.x;   // over M_TOT*96
    const int m  = idx / 96;
    const int c8 = idx % 96;
    const int c  = c8 * 8;
    const int h  = c8 >> 3;
    const size_t MN = (size_t)M_TOT * H_DIM;

    const float lsum = lp[m * NHEAD + h] + lp[M_TOT * NHEAD + m * NHEAD + h];
    const float inv  = 1.0f / lsum;

    bf16x8 a = *(const bf16x8*)(Pp + (size_t)m * H_DIM + c);
    bf16x8 b = *(const bf16x8*)(Pp + MN + (size_t)m * H_DIM + c);
    bf16x8 o;
    #pragma unroll
    for (int j = 0; j < 8; ++j)
        o[j] = (short)f2bf((bf2f((ushort)a[j]) + bf2f((ushort)b[j])) * inv);
    *(bf16x8*)(ctx + (size_t)m * H_DIM + c) = o;
}

// ---------------- LayerNorm ------------------------------------------------
__global__ __launch_bounds__(256)
void ln_kernel(const float* __restrict__ Hbuf, const float* __restrict__ gamma,
               const float* __restrict__ beta, float* __restrict__ out)
{
    const int m = blockIdx.x;
    const int t = threadIdx.x;
    const float* row = Hbuf + (size_t)m * H_DIM;
    __shared__ float red[256];
    float x[3];
    #pragma unroll
    for (int i = 0; i < 3; ++i) x[i] = row[t + i * 256];

    red[t] = x[0] + x[1] + x[2];
    __syncthreads();
    for (int off = 128; off > 0; off >>= 1) {
        if (t < off) red[t] += red[t + off];
        __syncthreads();
    }
    const float mu = red[0] * (1.0f / H_DIM);
    __syncthreads();

    float d0 = x[0] - mu, d1 = x[1] - mu, d2 = x[2] - mu;
    red[t] = d0 * d0 + d1 * d1 + d2 * d2;
    __syncthreads();
    for (int off = 128; off > 0; off >>= 1) {
        if (t < off) red[t] += red[t + off];
        __syncthreads();
    }
    const float var  = red[0] * (1.0f / H_DIM);
    const float rstd = rsqrtf(var + LN_EPS);
    #pragma unroll
    for (int i = 0; i < 3; ++i) {
        int c = t + i * 256;
        out[(size_t)m * H_DIM + c] = (x[i] - mu) * rstd * gamma[c] + beta[c];
    }
}

// ---------------------------------------------------------------------------
extern "C" void kernel_launch(void* const* d_in, const int* in_sizes, int n_in,
                              void* d_out, int out_size, void* d_ws, size_t ws_size,
                              hipStream_t stream)
{
    const float* hs   = (const float*)d_in[0];
    const float* mask = (const float*)d_in[1];
    const float* Wq   = (const float*)d_in[2];
    const float* bq   = (const float*)d_in[3];
    const float* Wk   = (const float*)d_in[4];
    const float* bk   = (const float*)d_in[5];
    const float* Wv   = (const float*)d_in[6];
    const float* bv   = (const float*)d_in[7];
    const float* Wo   = (const float*)d_in[8];
    const float* bo   = (const float*)d_in[9];
    const float* g    = (const float*)d_in[10];
    const float* be   = (const float*)d_in[11];
    float* out = (float*)d_out;

    char* base = (char*)d_ws;
    ushort* Xbf    = (ushort*)(base);                    //  6,291,456 B
    ushort* QKVbf  = (ushort*)(base + 6291456);          // 18,874,368 B
    ushort* Wcat   = (ushort*)(base + 25165824);         //  3,538,944 B (lp after QKV gemm)
    ushort* Wot    = (ushort*)(base + 28704768);         //  1,179,648 B
    float*  bcat   = (float*) (base + 29884416);         //      9,216 B
    ushort* Vt     = (ushort*)(base + 29893632);         //  6,291,456 B
    ushort* Cbf    = (ushort*)(base + 36185088);         //  6,291,456 B
    float*  Hb     = (float*) (base + 42476544);         // 12,582,912 B (Pp before out-GEMM)
    float*  lp     = (float*) (base + 25165824);         // reuse Wcat region (393,216 B)
    ushort* Pp     = (ushort*)(base + 42476544);         // reuse Hb region (12,582,912 B)

    convert_x<<<M_TOT * H_DIM / 1024, 256, 0, stream>>>(hs, Xbf);
    concat_bias<<<9, 256, 0, stream>>>(bq, bk, bv, bcat);
    convert_w<<<dim3(12, 12, 4), 256, 0, stream>>>(Wq, Wk, Wv, Wo, Wcat, Wot);

    // Q columns (< 768) pre-scaled by 0.125*log2(e) so attention can exp2 directly
    gemm_mfma<0><<<dim3(NQKV / 128, M_TOT / 128), 256, 0, stream>>>(
        Xbf, Wcat, bcat, nullptr, QKVbf, M_TOT, NQKV, H_DIM, 768, SM_C);

    transpose_v<<<dim3(S_LEN / 64, B_SZ * NHEAD), 256, 0, stream>>>(QKVbf + 1536, Vt);

    attn_mfma<<<dim3(S_LEN / ATT_QT, NHEAD, B_SZ * 2), 256, 0, stream>>>(
        QKVbf, QKVbf + 768, Vt, mask, Pp, lp);

    combine_kernel<<<M_TOT * 96 / 256, 256, 0, stream>>>(Pp, lp, Cbf);

    gemm_mfma<1><<<dim3(H_DIM / 128, M_TOT / 128), 256, 0, stream>>>(
        Cbf, Wot, bo, hs, Hb, M_TOT, H_DIM, H_DIM, 0, 1.0f);

    ln_kernel<<<M_TOT, 256, 0, stream>>>(Hb, g, be, out);
}